// Round 1
// baseline (1058.315 us; speedup 1.0000x reference)
//
#include <hip/hip_runtime.h>
#include <cstdint>

#define NN 40000
#define EE 640000
#define DD 128
#define HH 4
#define CC 32
#define LL 2
#define NEG_SLOPE 0.2f
#define ENC_NEG_INF 0x007FFFFFu

__device__ __forceinline__ unsigned enc_f32(float f) {
    unsigned b = __float_as_uint(f);
    return (b & 0x80000000u) ? ~b : (b | 0x80000000u);
}
__device__ __forceinline__ float dec_f32(unsigned e) {
    unsigned b = (e & 0x80000000u) ? (e & 0x7FFFFFFFu) : ~e;
    return __uint_as_float(b);
}

// Fused: xl = x@Wl+bl ; xr = x@Wr+br ; agg = x@Wres+bias   (8 rows / block)
__global__ __launch_bounds__(256) void gemm3_kernel(
    const float* __restrict__ x,
    const float* __restrict__ Wl, const float* __restrict__ bl,
    const float* __restrict__ Wr, const float* __restrict__ br,
    const float* __restrict__ Wres, const float* __restrict__ bias,
    float* __restrict__ xl, float* __restrict__ xr, float* __restrict__ agg)
{
    __shared__ float xs[8][DD];
    const int tid = threadIdx.x;
    const int row0 = blockIdx.x * 8;
    for (int i = tid; i < 8 * DD; i += 256) {
        xs[i >> 7][i & 127] = x[(size_t)row0 * DD + i];
    }
    __syncthreads();
    const int d  = tid & 127;
    const int r0 = (tid >> 7) << 2;   // 0 or 4

    const float* Wm[3] = {Wl, Wr, Wres};
    const float* bm[3] = {bl, br, bias};
    float* om[3] = {xl, xr, agg};
#pragma unroll
    for (int m = 0; m < 3; ++m) {
        const float* __restrict__ W = Wm[m];
        const float bv = bm[m][d];
        float acc0 = bv, acc1 = bv, acc2 = bv, acc3 = bv;
        for (int k = 0; k < DD; ++k) {
            const float w = W[k * DD + d];
            acc0 += xs[r0 + 0][k] * w;
            acc1 += xs[r0 + 1][k] * w;
            acc2 += xs[r0 + 2][k] * w;
            acc3 += xs[r0 + 3][k] * w;
        }
        float* o = om[m];
        o[(size_t)(row0 + r0 + 0) * DD + d] = acc0;
        o[(size_t)(row0 + r0 + 1) * DD + d] = acc1;
        o[(size_t)(row0 + r0 + 2) * DD + d] = acc2;
        o[(size_t)(row0 + r0 + 3) * DD + d] = acc3;
    }
}

__global__ __launch_bounds__(256) void init_amax_kernel(unsigned* __restrict__ amax)
{
    const int i = blockIdx.x * 256 + threadIdx.x;
    if (i < NN * HH) amax[i] = ENC_NEG_INF;
}

// one wave (64 lanes) per edge: alpha[e][h] = sum_c lrelu(xl[s]+xr[t])*att
__global__ __launch_bounds__(256) void score_kernel(
    const float* __restrict__ xl, const float* __restrict__ xr,
    const int* __restrict__ src, const int* __restrict__ dst,
    const float* __restrict__ att,
    float* __restrict__ alpha, unsigned* __restrict__ amax)
{
    const int e = (blockIdx.x * 256 + threadIdx.x) >> 6;
    const int lane = threadIdx.x & 63;
    if (e >= EE) return;
    const int s = src[e], t = dst[e];
    const float2 a2 = ((const float2*)(xl + (size_t)s * DD))[lane];
    const float2 b2 = ((const float2*)(xr + (size_t)t * DD))[lane];
    const float2 w2 = ((const float2*)att)[lane];
    float v0 = a2.x + b2.x; v0 = (v0 > 0.f) ? v0 : NEG_SLOPE * v0;
    float v1 = a2.y + b2.y; v1 = (v1 > 0.f) ? v1 : NEG_SLOPE * v1;
    float sum = v0 * w2.x + v1 * w2.y;
    sum += __shfl_xor(sum, 1);
    sum += __shfl_xor(sum, 2);
    sum += __shfl_xor(sum, 4);
    sum += __shfl_xor(sum, 8);
    if ((lane & 15) == 0) {
        const int h = lane >> 4;
        alpha[(size_t)e * HH + h] = sum;
        atomicMax(&amax[t * HH + h], enc_f32(sum));
    }
}

// decode amax in place (uint -> float), zero denom
__global__ __launch_bounds__(256) void fin_amax_kernel(
    unsigned* __restrict__ amax, float* __restrict__ denom)
{
    const int i = blockIdx.x * 256 + threadIdx.x;
    if (i < NN * HH) {
        const unsigned e = amax[i];
        const float m = (e == ENC_NEG_INF) ? 0.f : dec_f32(e);
        ((float*)amax)[i] = m;
        denom[i] = 0.f;
    }
}

// ex = exp(alpha - amax[dst]); alpha <- ex; denom[dst] += ex
__global__ __launch_bounds__(256) void expden_kernel(
    float* __restrict__ alpha, const float* __restrict__ amaxf,
    float* __restrict__ denom, const int* __restrict__ dst)
{
    const int i = blockIdx.x * 256 + threadIdx.x;
    if (i >= EE * HH) return;
    const int e = i >> 2, h = i & 3;
    const int t = dst[e];
    const float ex = __expf(alpha[i] - amaxf[t * HH + h]);
    alpha[i] = ex;
    atomicAdd(&denom[t * HH + h], ex);
}

// one wave per edge: agg[dst] += xl[src] * a[head]
__global__ __launch_bounds__(256) void scatter_kernel(
    const float* __restrict__ xl, const float* __restrict__ alpha,
    const float* __restrict__ denom,
    const int* __restrict__ src, const int* __restrict__ dst,
    float* __restrict__ agg)
{
    const int e = (blockIdx.x * 256 + threadIdx.x) >> 6;
    const int lane = threadIdx.x & 63;
    if (e >= EE) return;
    const int s = src[e], t = dst[e];
    float av = 0.f;
    if (lane < HH) av = alpha[(size_t)e * HH + lane] / (denom[t * HH + lane] + 1e-16f);
    const float a0 = __shfl(av, 0);
    const float a1 = __shfl(av, 1);
    const float a2 = __shfl(av, 2);
    const float a3 = __shfl(av, 3);
    const float aa = (lane < 32) ? a0 : a1;
    const float bb = (lane < 32) ? a2 : a3;
    atomicAdd(&agg[(size_t)t * DD + lane],      xl[(size_t)s * DD + lane]      * aa);
    atomicAdd(&agg[(size_t)t * DD + 64 + lane], xl[(size_t)s * DD + 64 + lane] * bb);
}

__global__ __launch_bounds__(256) void elu_kernel(
    const float* __restrict__ agg, float* __restrict__ out)
{
    const int i = blockIdx.x * 256 + threadIdx.x;
    if (i < NN * DD) {
        const float v = agg[i];
        out[i] = (v > 0.f) ? v : expm1f(v);
    }
}

extern "C" void kernel_launch(void* const* d_in, const int* in_sizes, int n_in,
                              void* d_out, int out_size, void* d_ws, size_t ws_size,
                              hipStream_t stream)
{
    const float* x0   = (const float*)d_in[0];
    const int*   ei   = (const int*)  d_in[1];
    const float* Wl   = (const float*)d_in[2];
    const float* bl   = (const float*)d_in[3];
    const float* Wr   = (const float*)d_in[4];
    const float* br   = (const float*)d_in[5];
    const float* att  = (const float*)d_in[6];
    const float* Wres = (const float*)d_in[7];
    const float* bias = (const float*)d_in[8];
    const int* src = ei;
    const int* dst = ei + EE;

    float* p = (float*)d_ws;
    float* xl    = p; p += (size_t)NN * DD;
    float* xr    = p; p += (size_t)NN * DD;
    float* agg   = p; p += (size_t)NN * DD;
    float* xbuf  = p; p += (size_t)NN * DD;
    float* alpha = p; p += (size_t)EE * HH;
    unsigned* amax = (unsigned*)p; p += (size_t)NN * HH;
    float* denom = p; p += (size_t)NN * HH;

    for (int l = 0; l < LL; ++l) {
        const float* xin = (l == 0) ? x0 : xbuf;
        float* xout = (l == LL - 1) ? (float*)d_out : xbuf;
        gemm3_kernel<<<NN / 8, 256, 0, stream>>>(
            xin, Wl + (size_t)l * DD * DD, bl + l * DD,
            Wr + (size_t)l * DD * DD, br + l * DD,
            Wres + (size_t)l * DD * DD, bias + l * DD,
            xl, xr, agg);
        init_amax_kernel<<<(NN * HH + 255) / 256, 256, 0, stream>>>(amax);
        score_kernel<<<EE / 4, 256, 0, stream>>>(
            xl, xr, src, dst, att + (size_t)l * HH * CC, alpha, amax);
        fin_amax_kernel<<<(NN * HH + 255) / 256, 256, 0, stream>>>(amax, denom);
        expden_kernel<<<(EE * HH + 255) / 256, 256, 0, stream>>>(
            alpha, (const float*)amax, denom, dst);
        scatter_kernel<<<EE / 4, 256, 0, stream>>>(xl, alpha, denom, src, dst, agg);
        elu_kernel<<<(NN * DD + 255) / 256, 256, 0, stream>>>(agg, xout);
    }
}

// Round 2
// 444.035 us; speedup vs baseline: 2.3834x; 2.3834x over previous
//
#include <hip/hip_runtime.h>
#include <cstdint>

#define NN 40000
#define EE 640000
#define DD 128
#define HH 4
#define CC 32
#define LL 2
#define NEG_SLOPE 0.2f
#define NBLK 157   // ceil(NN/256)

// Fused: xl = x@Wl+bl ; xr = x@Wr+br ; res = x@Wres+bias   (8 rows / block)
__global__ __launch_bounds__(256) void gemm3_kernel(
    const float* __restrict__ x,
    const float* __restrict__ Wl, const float* __restrict__ bl,
    const float* __restrict__ Wr, const float* __restrict__ br,
    const float* __restrict__ Wres, const float* __restrict__ bias,
    float* __restrict__ xl, float* __restrict__ xr, float* __restrict__ res)
{
    __shared__ float xs[8][DD];
    const int tid = threadIdx.x;
    const int row0 = blockIdx.x * 8;
    for (int i = tid; i < 8 * DD; i += 256) {
        xs[i >> 7][i & 127] = x[(size_t)row0 * DD + i];
    }
    __syncthreads();
    const int d  = tid & 127;
    const int r0 = (tid >> 7) << 2;   // 0 or 4

    const float* Wm[3] = {Wl, Wr, Wres};
    const float* bm[3] = {bl, br, bias};
    float* om[3] = {xl, xr, res};
#pragma unroll
    for (int m = 0; m < 3; ++m) {
        const float* __restrict__ W = Wm[m];
        const float bv = bm[m][d];
        float acc0 = bv, acc1 = bv, acc2 = bv, acc3 = bv;
        for (int k = 0; k < DD; ++k) {
            const float w = W[k * DD + d];
            acc0 += xs[r0 + 0][k] * w;
            acc1 += xs[r0 + 1][k] * w;
            acc2 += xs[r0 + 2][k] * w;
            acc3 += xs[r0 + 3][k] * w;
        }
        float* o = om[m];
        o[(size_t)(row0 + r0 + 0) * DD + d] = acc0;
        o[(size_t)(row0 + r0 + 1) * DD + d] = acc1;
        o[(size_t)(row0 + r0 + 2) * DD + d] = acc2;
        o[(size_t)(row0 + r0 + 3) * DD + d] = acc3;
    }
}

// ---------------- CSR build (once per call; dst is layer-invariant) --------

__global__ __launch_bounds__(256) void zero_deg_kernel(int* __restrict__ deg)
{
    const int i = blockIdx.x * 256 + threadIdx.x;
    if (i < NN) deg[i] = 0;
}

__global__ __launch_bounds__(256) void hist_kernel(
    const int* __restrict__ dst, int* __restrict__ deg)
{
    const int e = blockIdx.x * 256 + threadIdx.x;
    if (e < EE) atomicAdd(&deg[dst[e]], 1);
}

// per-block exclusive scan of deg -> rowptr ; block totals -> blksum
__global__ __launch_bounds__(256) void scan1_kernel(
    const int* __restrict__ deg, int* __restrict__ rowptr, int* __restrict__ blksum)
{
    __shared__ int s[256];
    const int i = blockIdx.x * 256 + threadIdx.x;
    const int v = (i < NN) ? deg[i] : 0;
    s[threadIdx.x] = v;
    __syncthreads();
    for (int off = 1; off < 256; off <<= 1) {
        const int t = (threadIdx.x >= off) ? s[threadIdx.x - off] : 0;
        __syncthreads();
        s[threadIdx.x] += t;
        __syncthreads();
    }
    if (i < NN) rowptr[i] = s[threadIdx.x] - v;
    if (threadIdx.x == 255) blksum[blockIdx.x] = s[255];
}

// exclusive scan of blksum (NBLK <= 256), single block
__global__ __launch_bounds__(256) void scan2_kernel(int* __restrict__ blksum)
{
    __shared__ int s[256];
    const int v = (threadIdx.x < NBLK) ? blksum[threadIdx.x] : 0;
    s[threadIdx.x] = v;
    __syncthreads();
    for (int off = 1; off < 256; off <<= 1) {
        const int t = (threadIdx.x >= off) ? s[threadIdx.x - off] : 0;
        __syncthreads();
        s[threadIdx.x] += t;
        __syncthreads();
    }
    if (threadIdx.x < NBLK) blksum[threadIdx.x] = s[threadIdx.x] - v;
}

__global__ __launch_bounds__(256) void scan3_kernel(
    int* __restrict__ rowptr, const int* __restrict__ blksum, int* __restrict__ cursor)
{
    const int i = blockIdx.x * 256 + threadIdx.x;
    if (i < NN) {
        const int v = rowptr[i] + blksum[blockIdx.x];
        rowptr[i] = v;
        cursor[i] = v;
    }
    if (i == 0) rowptr[NN] = EE;
}

__global__ __launch_bounds__(256) void fill_kernel(
    const int* __restrict__ src, const int* __restrict__ dst,
    int* __restrict__ cursor, int* __restrict__ col)
{
    const int e = blockIdx.x * 256 + threadIdx.x;
    if (e < EE) {
        const int p = atomicAdd(&cursor[dst[e]], 1);
        col[p] = src[e];
    }
}

// ------------- fused score + online-softmax + aggregate + ELU --------------
// one wave per destination node
__global__ __launch_bounds__(256) void gather_kernel(
    const float* __restrict__ xl, const float* __restrict__ xr,
    const float* __restrict__ res,
    const int* __restrict__ rowptr, const int* __restrict__ col,
    const float* __restrict__ att,
    float* __restrict__ out)
{
    const int node = (blockIdx.x * 256 + threadIdx.x) >> 6;
    const int lane = threadIdx.x & 63;
    if (node >= NN) return;

    const float2 xrv  = ((const float2*)(xr + (size_t)node * DD))[lane];
    const float2 attv = ((const float2*)att)[lane];

    float m = -3.0e38f, d = 0.f, acc0 = 0.f, acc1 = 0.f;
    const int beg = rowptr[node], end = rowptr[node + 1];
    for (int p = beg; p < end; ++p) {
        const int s = col[p];
        const float2 xlv = ((const float2*)(xl + (size_t)s * DD))[lane];
        float v0 = xlv.x + xrv.x; v0 = (v0 > 0.f) ? v0 : NEG_SLOPE * v0;
        float v1 = xlv.y + xrv.y; v1 = (v1 > 0.f) ? v1 : NEG_SLOPE * v1;
        float a = v0 * attv.x + v1 * attv.y;
        a += __shfl_xor(a, 1);
        a += __shfl_xor(a, 2);
        a += __shfl_xor(a, 4);
        a += __shfl_xor(a, 8);
        const float nm    = fmaxf(m, a);
        const float scale = __expf(m - nm);
        const float w     = __expf(a - nm);
        d    = d * scale + w;
        acc0 = acc0 * scale + w * xlv.x;
        acc1 = acc1 * scale + w * xlv.y;
        m = nm;
    }
    const float inv = 1.f / (d + 1e-16f);
    const float2 rv = ((const float2*)(res + (size_t)node * DD))[lane];
    float o0 = acc0 * inv + rv.x;
    float o1 = acc1 * inv + rv.y;
    o0 = (o0 > 0.f) ? o0 : expm1f(o0);
    o1 = (o1 > 0.f) ? o1 : expm1f(o1);
    ((float2*)(out + (size_t)node * DD))[lane] = make_float2(o0, o1);
}

extern "C" void kernel_launch(void* const* d_in, const int* in_sizes, int n_in,
                              void* d_out, int out_size, void* d_ws, size_t ws_size,
                              hipStream_t stream)
{
    const float* x0   = (const float*)d_in[0];
    const int*   ei   = (const int*)  d_in[1];
    const float* Wl   = (const float*)d_in[2];
    const float* bl   = (const float*)d_in[3];
    const float* Wr   = (const float*)d_in[4];
    const float* br   = (const float*)d_in[5];
    const float* att  = (const float*)d_in[6];
    const float* Wres = (const float*)d_in[7];
    const float* bias = (const float*)d_in[8];
    const int* src = ei;
    const int* dst = ei + EE;

    float* p = (float*)d_ws;
    float* xl   = p; p += (size_t)NN * DD;
    float* xr   = p; p += (size_t)NN * DD;
    float* res  = p; p += (size_t)NN * DD;
    float* xbuf = p; p += (size_t)NN * DD;
    int* rowptr = (int*)p; p += NN + 1;
    int* deg    = (int*)p; p += NN;
    int* cursor = (int*)p; p += NN;
    int* blksum = (int*)p; p += NBLK;
    int* col    = (int*)p; p += EE;

    // CSR build (dst fixed across layers)
    zero_deg_kernel<<<NBLK, 256, 0, stream>>>(deg);
    hist_kernel<<<(EE + 255) / 256, 256, 0, stream>>>(dst, deg);
    scan1_kernel<<<NBLK, 256, 0, stream>>>(deg, rowptr, blksum);
    scan2_kernel<<<1, 256, 0, stream>>>(blksum);
    scan3_kernel<<<NBLK, 256, 0, stream>>>(rowptr, blksum, cursor);
    fill_kernel<<<(EE + 255) / 256, 256, 0, stream>>>(src, dst, cursor, col);

    for (int l = 0; l < LL; ++l) {
        const float* xin = (l == 0) ? x0 : xbuf;
        float* xout = (l == LL - 1) ? (float*)d_out : xbuf;
        gemm3_kernel<<<NN / 8, 256, 0, stream>>>(
            xin, Wl + (size_t)l * DD * DD, bl + l * DD,
            Wr + (size_t)l * DD * DD, br + l * DD,
            Wres + (size_t)l * DD * DD, bias + l * DD,
            xl, xr, res);
        gather_kernel<<<(NN * 64 + 255) / 256, 256, 0, stream>>>(
            xl, xr, res, rowptr, col, att + (size_t)l * HH * CC, xout);
    }
}

// Round 3
// 243.929 us; speedup vs baseline: 4.3386x; 1.8203x over previous
//
#include <hip/hip_runtime.h>
#include <cstdint>

#define NN 40000
#define EE 640000
#define DD 128
#define HH 4
#define CC 32
#define LL 2
#define NEG_SLOPE 0.2f
#define NBLK 157   // ceil(NN/256)

typedef __attribute__((ext_vector_type(8))) short bf16x8;
typedef __attribute__((ext_vector_type(4))) float f32x4;

__device__ __forceinline__ unsigned short f2bf(float f) {
    unsigned u = __float_as_uint(f);
    unsigned r = (u + 0x7FFFu + ((u >> 16) & 1)) >> 16;
    return (unsigned short)r;
}

__device__ __forceinline__ void gload16(const void* g, void* l) {
    __builtin_amdgcn_global_load_lds(
        (const __attribute__((address_space(1))) unsigned*)g,
        (__attribute__((address_space(3))) unsigned*)l, 16, 0, 0);
}

// x fp32 -> bf16 bits
__global__ __launch_bounds__(256) void cvt_kernel(
    const float* __restrict__ in, unsigned short* __restrict__ out)
{
    const int i = blockIdx.x * 256 + threadIdx.x;   // i < NN*DD/4
    if (i >= NN * DD / 4) return;
    const float4 v = ((const float4*)in)[i];
    ushort4 o;
    o.x = f2bf(v.x); o.y = f2bf(v.y); o.z = f2bf(v.z); o.w = f2bf(v.w);
    ((ushort4*)out)[i] = o;
}

// Pack W (fp32 [128][128] k-major, 3 matrices) into bf16 fragment order:
// Wb[nb*8192 + q*512 + n*8 + j] = W_sel[k = (q>>2)*32 + (q&3)*8 + j][(nb&1)*64 + n]
__global__ __launch_bounds__(256) void prepw_kernel(
    const float* __restrict__ Wl, const float* __restrict__ Wr,
    const float* __restrict__ Wres, unsigned short* __restrict__ Wb)
{
    const int i = blockIdx.x * 256 + threadIdx.x;   // i < 6*8192
    if (i >= 6 * 8192) return;
    const int nb = i >> 13;
    const int rem = i & 8191;
    const int q = rem >> 9;
    const int n = (rem >> 3) & 63;
    const int j = i & 7;
    const int k = (q >> 2) * 32 + (q & 3) * 8 + j;
    const int colg = (nb & 1) * 64 + n;
    const float* W = (nb < 2) ? Wl : (nb < 4) ? Wr : Wres;
    Wb[i] = f2bf(W[k * DD + colg]);
}

// MFMA GEMM: out[40000][384] = x_bf16 @ [Wl|Wr|Wres] + bias, split into xl/xr/res.
// Block = 64 rows x 64 cols; grid (625, 6); 4 waves, each 32x32 (2x2 MFMA tiles).
__global__ __launch_bounds__(256) void gemm_mfma_kernel(
    const unsigned short* __restrict__ xb, const unsigned short* __restrict__ Wb,
    const float* __restrict__ bl, const float* __restrict__ br,
    const float* __restrict__ bias,
    float* __restrict__ xl, float* __restrict__ xr, float* __restrict__ res)
{
    __shared__ __align__(16) unsigned short lds[16384];  // A:0..8191, B:8192..16383
    const int lane = threadIdx.x & 63;
    const int wv = threadIdx.x >> 6;
    const int row0 = blockIdx.x << 6;
    const int nb = blockIdx.y;

    // stage A (x rows, fragment-linear) and B (pre-packed, contiguous)
#pragma unroll
    for (int j = 0; j < 4; ++j) {
        const int q = j * 4 + wv;
        gload16(xb + (size_t)(row0 + lane) * DD + q * 8, &lds[q * 512]);
        gload16(Wb + nb * 8192 + q * 512 + lane * 8, &lds[8192 + q * 512]);
    }
    __syncthreads();

    const int wm = wv >> 1, wn = wv & 1;
    const int h = lane >> 4, r = lane & 15;
    f32x4 acc[2][2] = {{{0.f,0.f,0.f,0.f},{0.f,0.f,0.f,0.f}},
                       {{0.f,0.f,0.f,0.f},{0.f,0.f,0.f,0.f}}};
#pragma unroll
    for (int s = 0; s < 4; ++s) {
        const int base = (s * 4 + h) * 64;
        const bf16x8 a0 = *(const bf16x8*)&lds[(base + wm * 32 + r) * 8];
        const bf16x8 a1 = *(const bf16x8*)&lds[(base + wm * 32 + 16 + r) * 8];
        const bf16x8 b0 = *(const bf16x8*)&lds[8192 + (base + wn * 32 + r) * 8];
        const bf16x8 b1 = *(const bf16x8*)&lds[8192 + (base + wn * 32 + 16 + r) * 8];
        acc[0][0] = __builtin_amdgcn_mfma_f32_16x16x32_bf16(a0, b0, acc[0][0], 0, 0, 0);
        acc[0][1] = __builtin_amdgcn_mfma_f32_16x16x32_bf16(a0, b1, acc[0][1], 0, 0, 0);
        acc[1][0] = __builtin_amdgcn_mfma_f32_16x16x32_bf16(a1, b0, acc[1][0], 0, 0, 0);
        acc[1][1] = __builtin_amdgcn_mfma_f32_16x16x32_bf16(a1, b1, acc[1][1], 0, 0, 0);
    }

    float* const outp = (nb < 2) ? xl : (nb < 4) ? xr : res;
    const float* const bp = (nb < 2) ? bl : (nb < 4) ? br : bias;
    const int c0 = (nb & 1) * 64 + wn * 32;
#pragma unroll
    for (int ni = 0; ni < 2; ++ni) {
        const int col = c0 + ni * 16 + r;
        const float bv = bp[col];
#pragma unroll
        for (int mi = 0; mi < 2; ++mi) {
            const int rw = row0 + wm * 32 + mi * 16 + h * 4;
#pragma unroll
            for (int v = 0; v < 4; ++v)
                outp[(size_t)(rw + v) * DD + col] = acc[mi][ni][v] + bv;
        }
    }
}

// ---------------- CSR build (once per call; dst is layer-invariant) --------

__global__ __launch_bounds__(256) void zero_deg_kernel(int* __restrict__ deg)
{
    const int i = blockIdx.x * 256 + threadIdx.x;
    if (i < NN) deg[i] = 0;
}

__global__ __launch_bounds__(256) void hist_kernel(
    const int* __restrict__ dst, int* __restrict__ deg)
{
    const int e = blockIdx.x * 256 + threadIdx.x;
    if (e < EE) atomicAdd(&deg[dst[e]], 1);
}

__global__ __launch_bounds__(256) void scan1_kernel(
    const int* __restrict__ deg, int* __restrict__ rowptr, int* __restrict__ blksum)
{
    __shared__ int s[256];
    const int i = blockIdx.x * 256 + threadIdx.x;
    const int v = (i < NN) ? deg[i] : 0;
    s[threadIdx.x] = v;
    __syncthreads();
    for (int off = 1; off < 256; off <<= 1) {
        const int t = (threadIdx.x >= off) ? s[threadIdx.x - off] : 0;
        __syncthreads();
        s[threadIdx.x] += t;
        __syncthreads();
    }
    if (i < NN) rowptr[i] = s[threadIdx.x] - v;
    if (threadIdx.x == 255) blksum[blockIdx.x] = s[255];
}

__global__ __launch_bounds__(256) void scan2_kernel(int* __restrict__ blksum)
{
    __shared__ int s[256];
    const int v = (threadIdx.x < NBLK) ? blksum[threadIdx.x] : 0;
    s[threadIdx.x] = v;
    __syncthreads();
    for (int off = 1; off < 256; off <<= 1) {
        const int t = (threadIdx.x >= off) ? s[threadIdx.x - off] : 0;
        __syncthreads();
        s[threadIdx.x] += t;
        __syncthreads();
    }
    if (threadIdx.x < NBLK) blksum[threadIdx.x] = s[threadIdx.x] - v;
}

__global__ __launch_bounds__(256) void scan3_kernel(
    int* __restrict__ rowptr, const int* __restrict__ blksum, int* __restrict__ cursor)
{
    const int i = blockIdx.x * 256 + threadIdx.x;
    if (i < NN) {
        const int v = rowptr[i] + blksum[blockIdx.x];
        rowptr[i] = v;
        cursor[i] = v;
    }
    if (i == 0) rowptr[NN] = EE;
}

__global__ __launch_bounds__(256) void fill_kernel(
    const int* __restrict__ src, const int* __restrict__ dst,
    int* __restrict__ cursor, int* __restrict__ col)
{
    const int e = blockIdx.x * 256 + threadIdx.x;
    if (e < EE) {
        const int p = atomicAdd(&cursor[dst[e]], 1);
        col[p] = src[e];
    }
}

// ------------- fused score + online-softmax + aggregate + ELU --------------
// one wave per destination node; edges unrolled x4 for memory-level parallelism
__global__ __launch_bounds__(256) void gather_kernel(
    const float* __restrict__ xl, const float* __restrict__ xr,
    const float* __restrict__ res,
    const int* __restrict__ rowptr, const int* __restrict__ col,
    const float* __restrict__ att,
    float* __restrict__ outf, unsigned short* __restrict__ outb)
{
    const int node = (blockIdx.x * 256 + threadIdx.x) >> 6;
    const int lane = threadIdx.x & 63;
    if (node >= NN) return;

    const float2 xrv  = ((const float2*)(xr + (size_t)node * DD))[lane];
    const float2 attv = ((const float2*)att)[lane];

    float m = -3.0e38f, d = 0.f, acc0 = 0.f, acc1 = 0.f;
    const int beg = rowptr[node], end = rowptr[node + 1];
    for (int p = beg; p < end; p += 4) {
        const int s0 = col[p];
        const int s1 = (p + 1 < end) ? col[p + 1] : s0;
        const int s2 = (p + 2 < end) ? col[p + 2] : s0;
        const int s3 = (p + 3 < end) ? col[p + 3] : s0;
        const float2 x0 = ((const float2*)(xl + (size_t)s0 * DD))[lane];
        const float2 x1 = ((const float2*)(xl + (size_t)s1 * DD))[lane];
        const float2 x2 = ((const float2*)(xl + (size_t)s2 * DD))[lane];
        const float2 x3 = ((const float2*)(xl + (size_t)s3 * DD))[lane];

        float v0, v1, a0, a1, a2, a3;
        v0 = x0.x + xrv.x; v0 = (v0 > 0.f) ? v0 : NEG_SLOPE * v0;
        v1 = x0.y + xrv.y; v1 = (v1 > 0.f) ? v1 : NEG_SLOPE * v1;
        a0 = v0 * attv.x + v1 * attv.y;
        v0 = x1.x + xrv.x; v0 = (v0 > 0.f) ? v0 : NEG_SLOPE * v0;
        v1 = x1.y + xrv.y; v1 = (v1 > 0.f) ? v1 : NEG_SLOPE * v1;
        a1 = v0 * attv.x + v1 * attv.y;
        v0 = x2.x + xrv.x; v0 = (v0 > 0.f) ? v0 : NEG_SLOPE * v0;
        v1 = x2.y + xrv.y; v1 = (v1 > 0.f) ? v1 : NEG_SLOPE * v1;
        a2 = v0 * attv.x + v1 * attv.y;
        v0 = x3.x + xrv.x; v0 = (v0 > 0.f) ? v0 : NEG_SLOPE * v0;
        v1 = x3.y + xrv.y; v1 = (v1 > 0.f) ? v1 : NEG_SLOPE * v1;
        a3 = v0 * attv.x + v1 * attv.y;
#pragma unroll
        for (int o = 1; o <= 8; o <<= 1) {
            a0 += __shfl_xor(a0, o);
            a1 += __shfl_xor(a1, o);
            a2 += __shfl_xor(a2, o);
            a3 += __shfl_xor(a3, o);
        }
        if (p + 1 >= end) a1 = -3.0e38f;
        if (p + 2 >= end) a2 = -3.0e38f;
        if (p + 3 >= end) a3 = -3.0e38f;

        const float cm = fmaxf(fmaxf(a0, a1), fmaxf(a2, a3));
        const float nm = fmaxf(m, cm);
        const float sc = __expf(m - nm);
        const float w0 = __expf(a0 - nm);
        const float w1 = __expf(a1 - nm);
        const float w2 = __expf(a2 - nm);
        const float w3 = __expf(a3 - nm);
        d    = d    * sc + w0 + w1 + w2 + w3;
        acc0 = acc0 * sc + w0 * x0.x + w1 * x1.x + w2 * x2.x + w3 * x3.x;
        acc1 = acc1 * sc + w0 * x0.y + w1 * x1.y + w2 * x2.y + w3 * x3.y;
        m = nm;
    }
    const float inv = 1.f / (d + 1e-16f);
    const float2 rv = ((const float2*)(res + (size_t)node * DD))[lane];
    float o0 = acc0 * inv + rv.x;
    float o1 = acc1 * inv + rv.y;
    o0 = (o0 > 0.f) ? o0 : expm1f(o0);
    o1 = (o1 > 0.f) ? o1 : expm1f(o1);
    if (outf) ((float2*)(outf + (size_t)node * DD))[lane] = make_float2(o0, o1);
    if (outb) {
        ushort2 ob; ob.x = f2bf(o0); ob.y = f2bf(o1);
        ((ushort2*)(outb + (size_t)node * DD))[lane] = ob;
    }
}

extern "C" void kernel_launch(void* const* d_in, const int* in_sizes, int n_in,
                              void* d_out, int out_size, void* d_ws, size_t ws_size,
                              hipStream_t stream)
{
    const float* x0   = (const float*)d_in[0];
    const int*   ei   = (const int*)  d_in[1];
    const float* Wl   = (const float*)d_in[2];
    const float* bl   = (const float*)d_in[3];
    const float* Wr   = (const float*)d_in[4];
    const float* br   = (const float*)d_in[5];
    const float* att  = (const float*)d_in[6];
    const float* Wres = (const float*)d_in[7];
    const float* bias = (const float*)d_in[8];
    const int* src = ei;
    const int* dst = ei + EE;

    float* p = (float*)d_ws;
    float* xl   = p; p += (size_t)NN * DD;
    float* xr   = p; p += (size_t)NN * DD;
    float* res  = p; p += (size_t)NN * DD;
    unsigned short* xb0 = (unsigned short*)p; p += (size_t)NN * DD / 2;
    unsigned short* xb1 = (unsigned short*)p; p += (size_t)NN * DD / 2;
    unsigned short* Wb  = (unsigned short*)p; p += 6 * 8192 / 2;
    int* rowptr = (int*)p; p += NN + 1;
    int* deg    = (int*)p; p += NN;
    int* cursor = (int*)p; p += NN;
    int* blksum = (int*)p; p += NBLK;
    int* col    = (int*)p; p += EE;

    // CSR build (dst fixed across layers)
    zero_deg_kernel<<<NBLK, 256, 0, stream>>>(deg);
    hist_kernel<<<(EE + 255) / 256, 256, 0, stream>>>(dst, deg);
    scan1_kernel<<<NBLK, 256, 0, stream>>>(deg, rowptr, blksum);
    scan2_kernel<<<1, 256, 0, stream>>>(blksum);
    scan3_kernel<<<NBLK, 256, 0, stream>>>(rowptr, blksum, cursor);
    fill_kernel<<<(EE + 255) / 256, 256, 0, stream>>>(src, dst, cursor, col);

    cvt_kernel<<<(NN * DD / 4 + 255) / 256, 256, 0, stream>>>(x0, xb0);

    for (int l = 0; l < LL; ++l) {
        const unsigned short* xin = (l == 0) ? xb0 : xb1;
        prepw_kernel<<<192, 256, 0, stream>>>(
            Wl + (size_t)l * DD * DD, Wr + (size_t)l * DD * DD,
            Wres + (size_t)l * DD * DD, Wb);
        gemm_mfma_kernel<<<dim3(NN / 64, 6), 256, 0, stream>>>(
            xin, Wb, bl + l * DD, br + l * DD, bias + l * DD, xl, xr, res);
        gather_kernel<<<(NN * 64 + 255) / 256, 256, 0, stream>>>(
            xl, xr, res, rowptr, col, att + (size_t)l * HH * CC,
            (l == LL - 1) ? (float*)d_out : nullptr,
            (l == 0) ? xb1 : nullptr);
    }
}

// Round 4
// 221.131 us; speedup vs baseline: 4.7859x; 1.1031x over previous
//
#include <hip/hip_runtime.h>
#include <cstdint>

#define NN 40000
#define EE 640000
#define DD 128
#define HH 4
#define CC 32
#define LL 2
#define NEG_SLOPE 0.2f
#define NBLK 157   // ceil(NN/256)

typedef __attribute__((ext_vector_type(8))) short bf16x8;
typedef __attribute__((ext_vector_type(4))) float f32x4;

__device__ __forceinline__ unsigned short f2bf(float f) {
    unsigned u = __float_as_uint(f);
    unsigned r = (u + 0x7FFFu + ((u >> 16) & 1)) >> 16;
    return (unsigned short)r;
}
__device__ __forceinline__ float bf2f(unsigned short u) {
    return __uint_as_float(((unsigned)u) << 16);
}

__device__ __forceinline__ void gload16(const void* g, void* l) {
    __builtin_amdgcn_global_load_lds(
        (const __attribute__((address_space(1))) unsigned*)g,
        (__attribute__((address_space(3))) unsigned*)l, 16, 0, 0);
}

// x fp32 -> bf16 bits
__global__ __launch_bounds__(256) void cvt_kernel(
    const float* __restrict__ in, unsigned short* __restrict__ out)
{
    const int i = blockIdx.x * 256 + threadIdx.x;   // i < NN*DD/4
    if (i >= NN * DD / 4) return;
    const float4 v = ((const float4*)in)[i];
    ushort4 o;
    o.x = f2bf(v.x); o.y = f2bf(v.y); o.z = f2bf(v.z); o.w = f2bf(v.w);
    ((ushort4*)out)[i] = o;
}

// Pack W (fp32 [128][128] k-major, 3 matrices) into bf16 fragment order:
// Wb[nb*8192 + q*512 + n*8 + j] = W_sel[k = (q>>2)*32 + (q&3)*8 + j][(nb&1)*64 + n]
__global__ __launch_bounds__(256) void prepw_kernel(
    const float* __restrict__ Wl, const float* __restrict__ Wr,
    const float* __restrict__ Wres, unsigned short* __restrict__ Wb)
{
    const int i = blockIdx.x * 256 + threadIdx.x;   // i < 6*8192
    if (i >= 6 * 8192) return;
    const int nb = i >> 13;
    const int rem = i & 8191;
    const int q = rem >> 9;
    const int n = (rem >> 3) & 63;
    const int j = i & 7;
    const int k = (q >> 2) * 32 + (q & 3) * 8 + j;
    const int colg = (nb & 1) * 64 + n;
    const float* W = (nb < 2) ? Wl : (nb < 4) ? Wr : Wres;
    Wb[i] = f2bf(W[k * DD + colg]);
}

// MFMA GEMM: [40000][384] = x_bf16 @ [Wl|Wr|Wres] + bias -> xl(bf16), xr(f32), res(f32).
// Block = 64 rows x 64 cols; grid (625, 6); 4 waves, each 32x32 (2x2 MFMA tiles).
__global__ __launch_bounds__(256) void gemm_mfma_kernel(
    const unsigned short* __restrict__ xb, const unsigned short* __restrict__ Wb,
    const float* __restrict__ bl, const float* __restrict__ br,
    const float* __restrict__ bias,
    unsigned short* __restrict__ xlb, float* __restrict__ xr, float* __restrict__ res)
{
    __shared__ __align__(16) unsigned short lds[16384];  // A:0..8191, B:8192..16383
    const int lane = threadIdx.x & 63;
    const int wv = threadIdx.x >> 6;
    const int row0 = blockIdx.x << 6;
    const int nb = blockIdx.y;

#pragma unroll
    for (int j = 0; j < 4; ++j) {
        const int q = j * 4 + wv;
        gload16(xb + (size_t)(row0 + lane) * DD + q * 8, &lds[q * 512]);
        gload16(Wb + nb * 8192 + q * 512 + lane * 8, &lds[8192 + q * 512]);
    }
    __syncthreads();

    const int wm = wv >> 1, wn = wv & 1;
    const int h = lane >> 4, r = lane & 15;
    f32x4 acc[2][2] = {{{0.f,0.f,0.f,0.f},{0.f,0.f,0.f,0.f}},
                       {{0.f,0.f,0.f,0.f},{0.f,0.f,0.f,0.f}}};
#pragma unroll
    for (int s = 0; s < 4; ++s) {
        const int base = (s * 4 + h) * 64;
        const bf16x8 a0 = *(const bf16x8*)&lds[(base + wm * 32 + r) * 8];
        const bf16x8 a1 = *(const bf16x8*)&lds[(base + wm * 32 + 16 + r) * 8];
        const bf16x8 b0 = *(const bf16x8*)&lds[8192 + (base + wn * 32 + r) * 8];
        const bf16x8 b1 = *(const bf16x8*)&lds[8192 + (base + wn * 32 + 16 + r) * 8];
        acc[0][0] = __builtin_amdgcn_mfma_f32_16x16x32_bf16(a0, b0, acc[0][0], 0, 0, 0);
        acc[0][1] = __builtin_amdgcn_mfma_f32_16x16x32_bf16(a0, b1, acc[0][1], 0, 0, 0);
        acc[1][0] = __builtin_amdgcn_mfma_f32_16x16x32_bf16(a1, b0, acc[1][0], 0, 0, 0);
        acc[1][1] = __builtin_amdgcn_mfma_f32_16x16x32_bf16(a1, b1, acc[1][1], 0, 0, 0);
    }

    const float* const bp = (nb < 2) ? bl : (nb < 4) ? br : bias;
    const int c0 = (nb & 1) * 64 + wn * 32;
#pragma unroll
    for (int ni = 0; ni < 2; ++ni) {
        const int col = c0 + ni * 16 + r;
        const float bv = bp[col];
#pragma unroll
        for (int mi = 0; mi < 2; ++mi) {
            const int rw = row0 + wm * 32 + mi * 16 + h * 4;
            if (nb < 2) {
#pragma unroll
                for (int v = 0; v < 4; ++v)
                    xlb[(size_t)(rw + v) * DD + col] = f2bf(acc[mi][ni][v] + bv);
            } else {
                float* const o = (nb < 4) ? xr : res;
#pragma unroll
                for (int v = 0; v < 4; ++v)
                    o[(size_t)(rw + v) * DD + col] = acc[mi][ni][v] + bv;
            }
        }
    }
}

// ---------------- CSR build (once per call; dst is layer-invariant) --------

__global__ __launch_bounds__(256) void zero_deg_kernel(int* __restrict__ deg)
{
    const int i = blockIdx.x * 256 + threadIdx.x;
    if (i < NN) deg[i] = 0;
}

__global__ __launch_bounds__(256) void hist_kernel(
    const int* __restrict__ dst, int* __restrict__ deg)
{
    const int e = blockIdx.x * 256 + threadIdx.x;
    if (e < EE) atomicAdd(&deg[dst[e]], 1);
}

__global__ __launch_bounds__(256) void scan1_kernel(
    const int* __restrict__ deg, int* __restrict__ rowptr, int* __restrict__ blksum)
{
    __shared__ int s[256];
    const int i = blockIdx.x * 256 + threadIdx.x;
    const int v = (i < NN) ? deg[i] : 0;
    s[threadIdx.x] = v;
    __syncthreads();
    for (int off = 1; off < 256; off <<= 1) {
        const int t = (threadIdx.x >= off) ? s[threadIdx.x - off] : 0;
        __syncthreads();
        s[threadIdx.x] += t;
        __syncthreads();
    }
    if (i < NN) rowptr[i] = s[threadIdx.x] - v;
    if (threadIdx.x == 255) blksum[blockIdx.x] = s[255];
}

__global__ __launch_bounds__(256) void scan2_kernel(int* __restrict__ blksum)
{
    __shared__ int s[256];
    const int v = (threadIdx.x < NBLK) ? blksum[threadIdx.x] : 0;
    s[threadIdx.x] = v;
    __syncthreads();
    for (int off = 1; off < 256; off <<= 1) {
        const int t = (threadIdx.x >= off) ? s[threadIdx.x - off] : 0;
        __syncthreads();
        s[threadIdx.x] += t;
        __syncthreads();
    }
    if (threadIdx.x < NBLK) blksum[threadIdx.x] = s[threadIdx.x] - v;
}

__global__ __launch_bounds__(256) void scan3_kernel(
    int* __restrict__ rowptr, const int* __restrict__ blksum, int* __restrict__ cursor)
{
    const int i = blockIdx.x * 256 + threadIdx.x;
    if (i < NN) {
        const int v = rowptr[i] + blksum[blockIdx.x];
        rowptr[i] = v;
        cursor[i] = v;
    }
    if (i == 0) rowptr[NN] = EE;
}

__global__ __launch_bounds__(256) void fill_kernel(
    const int* __restrict__ src, const int* __restrict__ dst,
    int* __restrict__ cursor, int* __restrict__ col)
{
    const int e = blockIdx.x * 256 + threadIdx.x;
    if (e < EE) {
        const int p = atomicAdd(&cursor[dst[e]], 1);
        col[p] = src[e];
    }
}

// ------------- fused score + online-softmax + aggregate + ELU --------------
// one wave per destination node; edges unrolled x4; xl gathered as bf16
__global__ __launch_bounds__(256) void gather_kernel(
    const unsigned short* __restrict__ xlb, const float* __restrict__ xr,
    const float* __restrict__ res,
    const int* __restrict__ rowptr, const int* __restrict__ col,
    const float* __restrict__ att,
    float* __restrict__ outf, unsigned short* __restrict__ outb)
{
    const int node = (blockIdx.x * 256 + threadIdx.x) >> 6;
    const int lane = threadIdx.x & 63;
    if (node >= NN) return;

    const float2 xrv  = ((const float2*)(xr + (size_t)node * DD))[lane];
    const float2 attv = ((const float2*)att)[lane];

    float m = -3.0e38f, d = 0.f, acc0 = 0.f, acc1 = 0.f;
    const int beg = rowptr[node], end = rowptr[node + 1];
    for (int p = beg; p < end; p += 4) {
        const int s0 = col[p];
        const int s1 = (p + 1 < end) ? col[p + 1] : s0;
        const int s2 = (p + 2 < end) ? col[p + 2] : s0;
        const int s3 = (p + 3 < end) ? col[p + 3] : s0;
        const ushort2 u0 = ((const ushort2*)(xlb + (size_t)s0 * DD))[lane];
        const ushort2 u1 = ((const ushort2*)(xlb + (size_t)s1 * DD))[lane];
        const ushort2 u2 = ((const ushort2*)(xlb + (size_t)s2 * DD))[lane];
        const ushort2 u3 = ((const ushort2*)(xlb + (size_t)s3 * DD))[lane];
        const float x0x = bf2f(u0.x), x0y = bf2f(u0.y);
        const float x1x = bf2f(u1.x), x1y = bf2f(u1.y);
        const float x2x = bf2f(u2.x), x2y = bf2f(u2.y);
        const float x3x = bf2f(u3.x), x3y = bf2f(u3.y);

        float v0, v1, a0, a1, a2, a3;
        v0 = x0x + xrv.x; v0 = (v0 > 0.f) ? v0 : NEG_SLOPE * v0;
        v1 = x0y + xrv.y; v1 = (v1 > 0.f) ? v1 : NEG_SLOPE * v1;
        a0 = v0 * attv.x + v1 * attv.y;
        v0 = x1x + xrv.x; v0 = (v0 > 0.f) ? v0 : NEG_SLOPE * v0;
        v1 = x1y + xrv.y; v1 = (v1 > 0.f) ? v1 : NEG_SLOPE * v1;
        a1 = v0 * attv.x + v1 * attv.y;
        v0 = x2x + xrv.x; v0 = (v0 > 0.f) ? v0 : NEG_SLOPE * v0;
        v1 = x2y + xrv.y; v1 = (v1 > 0.f) ? v1 : NEG_SLOPE * v1;
        a2 = v0 * attv.x + v1 * attv.y;
        v0 = x3x + xrv.x; v0 = (v0 > 0.f) ? v0 : NEG_SLOPE * v0;
        v1 = x3y + xrv.y; v1 = (v1 > 0.f) ? v1 : NEG_SLOPE * v1;
        a3 = v0 * attv.x + v1 * attv.y;
#pragma unroll
        for (int o = 1; o <= 8; o <<= 1) {
            a0 += __shfl_xor(a0, o);
            a1 += __shfl_xor(a1, o);
            a2 += __shfl_xor(a2, o);
            a3 += __shfl_xor(a3, o);
        }
        if (p + 1 >= end) a1 = -3.0e38f;
        if (p + 2 >= end) a2 = -3.0e38f;
        if (p + 3 >= end) a3 = -3.0e38f;

        const float cm = fmaxf(fmaxf(a0, a1), fmaxf(a2, a3));
        const float nm = fmaxf(m, cm);
        const float sc = __expf(m - nm);
        const float w0 = __expf(a0 - nm);
        const float w1 = __expf(a1 - nm);
        const float w2 = __expf(a2 - nm);
        const float w3 = __expf(a3 - nm);
        d    = d    * sc + w0 + w1 + w2 + w3;
        acc0 = acc0 * sc + w0 * x0x + w1 * x1x + w2 * x2x + w3 * x3x;
        acc1 = acc1 * sc + w0 * x0y + w1 * x1y + w2 * x2y + w3 * x3y;
        m = nm;
    }
    const float inv = 1.f / (d + 1e-16f);
    const float2 rv = ((const float2*)(res + (size_t)node * DD))[lane];
    float o0 = acc0 * inv + rv.x;
    float o1 = acc1 * inv + rv.y;
    o0 = (o0 > 0.f) ? o0 : expm1f(o0);
    o1 = (o1 > 0.f) ? o1 : expm1f(o1);
    if (outf) ((float2*)(outf + (size_t)node * DD))[lane] = make_float2(o0, o1);
    if (outb) {
        ushort2 ob; ob.x = f2bf(o0); ob.y = f2bf(o1);
        ((ushort2*)(outb + (size_t)node * DD))[lane] = ob;
    }
}

extern "C" void kernel_launch(void* const* d_in, const int* in_sizes, int n_in,
                              void* d_out, int out_size, void* d_ws, size_t ws_size,
                              hipStream_t stream)
{
    const float* x0   = (const float*)d_in[0];
    const int*   ei   = (const int*)  d_in[1];
    const float* Wl   = (const float*)d_in[2];
    const float* bl   = (const float*)d_in[3];
    const float* Wr   = (const float*)d_in[4];
    const float* br   = (const float*)d_in[5];
    const float* att  = (const float*)d_in[6];
    const float* Wres = (const float*)d_in[7];
    const float* bias = (const float*)d_in[8];
    const int* src = ei;
    const int* dst = ei + EE;

    float* p = (float*)d_ws;
    float* xr   = p; p += (size_t)NN * DD;
    float* res  = p; p += (size_t)NN * DD;
    unsigned short* xlb = (unsigned short*)p; p += (size_t)NN * DD / 2;
    unsigned short* xb0 = (unsigned short*)p; p += (size_t)NN * DD / 2;
    unsigned short* xb1 = (unsigned short*)p; p += (size_t)NN * DD / 2;
    unsigned short* Wb  = (unsigned short*)p; p += 6 * 8192 / 2;
    int* rowptr = (int*)p; p += NN + 1;
    int* deg    = (int*)p; p += NN;
    int* cursor = (int*)p; p += NN;
    int* blksum = (int*)p; p += NBLK;
    int* col    = (int*)p; p += EE;

    // CSR build (dst fixed across layers)
    zero_deg_kernel<<<NBLK, 256, 0, stream>>>(deg);
    hist_kernel<<<(EE + 255) / 256, 256, 0, stream>>>(dst, deg);
    scan1_kernel<<<NBLK, 256, 0, stream>>>(deg, rowptr, blksum);
    scan2_kernel<<<1, 256, 0, stream>>>(blksum);
    scan3_kernel<<<NBLK, 256, 0, stream>>>(rowptr, blksum, cursor);
    fill_kernel<<<(EE + 255) / 256, 256, 0, stream>>>(src, dst, cursor, col);

    cvt_kernel<<<(NN * DD / 4 + 255) / 256, 256, 0, stream>>>(x0, xb0);

    for (int l = 0; l < LL; ++l) {
        const unsigned short* xin = (l == 0) ? xb0 : xb1;
        prepw_kernel<<<192, 256, 0, stream>>>(
            Wl + (size_t)l * DD * DD, Wr + (size_t)l * DD * DD,
            Wres + (size_t)l * DD * DD, Wb);
        gemm_mfma_kernel<<<dim3(NN / 64, 6), 256, 0, stream>>>(
            xin, Wb, bl + l * DD, br + l * DD, bias + l * DD, xlb, xr, res);
        gather_kernel<<<(NN * 64 + 255) / 256, 256, 0, stream>>>(
            xlb, xr, res, rowptr, col, att + (size_t)l * HH * CC,
            (l == LL - 1) ? (float*)d_out : nullptr,
            (l == 0) ? xb1 : nullptr);
    }
}

// Round 5
// 200.936 us; speedup vs baseline: 5.2669x; 1.1005x over previous
//
#include <hip/hip_runtime.h>
#include <cstdint>

#define NN 40000
#define EE 640000
#define DD 128
#define HH 4
#define CC 32
#define LL 2
#define NEG_SLOPE 0.2f
#define NBLK 157   // ceil(NN/256)

typedef __attribute__((ext_vector_type(8))) short bf16x8;
typedef __attribute__((ext_vector_type(4))) float f32x4;

__device__ __forceinline__ unsigned short f2bf(float f) {
    unsigned u = __float_as_uint(f);
    unsigned r = (u + 0x7FFFu + ((u >> 16) & 1)) >> 16;
    return (unsigned short)r;
}
__device__ __forceinline__ float bf2f(unsigned short u) {
    return __uint_as_float(((unsigned)u) << 16);
}

__device__ __forceinline__ void gload16(const void* g, void* l) {
    __builtin_amdgcn_global_load_lds(
        (const __attribute__((address_space(1))) unsigned*)g,
        (__attribute__((address_space(3))) unsigned*)l, 16, 0, 0);
}

// x fp32 -> bf16 bits
__global__ __launch_bounds__(256) void cvt_kernel(
    const float* __restrict__ in, unsigned short* __restrict__ out)
{
    const int i = blockIdx.x * 256 + threadIdx.x;   // i < NN*DD/4
    if (i >= NN * DD / 4) return;
    const float4 v = ((const float4*)in)[i];
    ushort4 o;
    o.x = f2bf(v.x); o.y = f2bf(v.y); o.z = f2bf(v.z); o.w = f2bf(v.w);
    ((ushort4*)out)[i] = o;
}

// Pack W (fp32 [128][128] k-major, 3 matrices) into bf16 fragment order:
// Wb[nb*8192 + q*512 + n*8 + j] = W_sel[k = (q>>2)*32 + (q&3)*8 + j][(nb&1)*64 + n]
__global__ __launch_bounds__(256) void prepw_kernel(
    const float* __restrict__ Wl, const float* __restrict__ Wr,
    const float* __restrict__ Wres, unsigned short* __restrict__ Wb)
{
    const int i = blockIdx.x * 256 + threadIdx.x;   // i < 6*8192
    if (i >= 6 * 8192) return;
    const int nb = i >> 13;
    const int rem = i & 8191;
    const int q = rem >> 9;
    const int n = (rem >> 3) & 63;
    const int j = i & 7;
    const int k = (q >> 2) * 32 + (q & 3) * 8 + j;
    const int colg = (nb & 1) * 64 + n;
    const float* W = (nb < 2) ? Wl : (nb < 4) ? Wr : Wres;
    Wb[i] = f2bf(W[k * DD + colg]);
}

// MFMA GEMM: [40000][384] = x_bf16 @ [Wl|Wr|Wres] + bias -> xl/xr/res all bf16.
// Block = 64 rows x 64 cols; grid (625, 6); 4 waves, each 32x32 (2x2 MFMA tiles).
__global__ __launch_bounds__(256) void gemm_mfma_kernel(
    const unsigned short* __restrict__ xb, const unsigned short* __restrict__ Wb,
    const float* __restrict__ bl, const float* __restrict__ br,
    const float* __restrict__ bias,
    unsigned short* __restrict__ xlb, unsigned short* __restrict__ xrb,
    unsigned short* __restrict__ resb)
{
    __shared__ __align__(16) unsigned short lds[16384];  // A:0..8191, B:8192..16383
    const int lane = threadIdx.x & 63;
    const int wv = threadIdx.x >> 6;
    const int row0 = blockIdx.x << 6;
    const int nb = blockIdx.y;

#pragma unroll
    for (int j = 0; j < 4; ++j) {
        const int q = j * 4 + wv;
        gload16(xb + (size_t)(row0 + lane) * DD + q * 8, &lds[q * 512]);
        gload16(Wb + nb * 8192 + q * 512 + lane * 8, &lds[8192 + q * 512]);
    }
    __syncthreads();

    const int wm = wv >> 1, wn = wv & 1;
    const int h = lane >> 4, r = lane & 15;
    f32x4 acc[2][2] = {{{0.f,0.f,0.f,0.f},{0.f,0.f,0.f,0.f}},
                       {{0.f,0.f,0.f,0.f},{0.f,0.f,0.f,0.f}}};
#pragma unroll
    for (int s = 0; s < 4; ++s) {
        const int base = (s * 4 + h) * 64;
        const bf16x8 a0 = *(const bf16x8*)&lds[(base + wm * 32 + r) * 8];
        const bf16x8 a1 = *(const bf16x8*)&lds[(base + wm * 32 + 16 + r) * 8];
        const bf16x8 b0 = *(const bf16x8*)&lds[8192 + (base + wn * 32 + r) * 8];
        const bf16x8 b1 = *(const bf16x8*)&lds[8192 + (base + wn * 32 + 16 + r) * 8];
        acc[0][0] = __builtin_amdgcn_mfma_f32_16x16x32_bf16(a0, b0, acc[0][0], 0, 0, 0);
        acc[0][1] = __builtin_amdgcn_mfma_f32_16x16x32_bf16(a0, b1, acc[0][1], 0, 0, 0);
        acc[1][0] = __builtin_amdgcn_mfma_f32_16x16x32_bf16(a1, b0, acc[1][0], 0, 0, 0);
        acc[1][1] = __builtin_amdgcn_mfma_f32_16x16x32_bf16(a1, b1, acc[1][1], 0, 0, 0);
    }

    unsigned short* const outp = (nb < 2) ? xlb : (nb < 4) ? xrb : resb;
    const float* const bp = (nb < 2) ? bl : (nb < 4) ? br : bias;
    const int c0 = (nb & 1) * 64 + wn * 32;
#pragma unroll
    for (int ni = 0; ni < 2; ++ni) {
        const int col = c0 + ni * 16 + r;
        const float bv = bp[col];
#pragma unroll
        for (int mi = 0; mi < 2; ++mi) {
            const int rw = row0 + wm * 32 + mi * 16 + h * 4;
#pragma unroll
            for (int v = 0; v < 4; ++v)
                outp[(size_t)(rw + v) * DD + col] = f2bf(acc[mi][ni][v] + bv);
        }
    }
}

// ---------------- CSR build (once per call; dst is layer-invariant) --------

__global__ __launch_bounds__(256) void zero_deg_kernel(int* __restrict__ deg)
{
    const int i = blockIdx.x * 256 + threadIdx.x;
    if (i < NN) deg[i] = 0;
}

__global__ __launch_bounds__(256) void hist_kernel(
    const int* __restrict__ dst, int* __restrict__ deg)
{
    const int e = blockIdx.x * 256 + threadIdx.x;
    if (e < EE) atomicAdd(&deg[dst[e]], 1);
}

__global__ __launch_bounds__(256) void scan1_kernel(
    const int* __restrict__ deg, int* __restrict__ rowptr, int* __restrict__ blksum)
{
    __shared__ int s[256];
    const int i = blockIdx.x * 256 + threadIdx.x;
    const int v = (i < NN) ? deg[i] : 0;
    s[threadIdx.x] = v;
    __syncthreads();
    for (int off = 1; off < 256; off <<= 1) {
        const int t = (threadIdx.x >= off) ? s[threadIdx.x - off] : 0;
        __syncthreads();
        s[threadIdx.x] += t;
        __syncthreads();
    }
    if (i < NN) rowptr[i] = s[threadIdx.x] - v;
    if (threadIdx.x == 255) blksum[blockIdx.x] = s[255];
}

__global__ __launch_bounds__(256) void scan2_kernel(int* __restrict__ blksum)
{
    __shared__ int s[256];
    const int v = (threadIdx.x < NBLK) ? blksum[threadIdx.x] : 0;
    s[threadIdx.x] = v;
    __syncthreads();
    for (int off = 1; off < 256; off <<= 1) {
        const int t = (threadIdx.x >= off) ? s[threadIdx.x - off] : 0;
        __syncthreads();
        s[threadIdx.x] += t;
        __syncthreads();
    }
    if (threadIdx.x < NBLK) blksum[threadIdx.x] = s[threadIdx.x] - v;
}

__global__ __launch_bounds__(256) void scan3_kernel(
    int* __restrict__ rowptr, const int* __restrict__ blksum, int* __restrict__ cursor)
{
    const int i = blockIdx.x * 256 + threadIdx.x;
    if (i < NN) {
        const int v = rowptr[i] + blksum[blockIdx.x];
        rowptr[i] = v;
        cursor[i] = v;
    }
    if (i == 0) rowptr[NN] = EE;
}

__global__ __launch_bounds__(256) void fill_kernel(
    const int* __restrict__ src, const int* __restrict__ dst,
    int* __restrict__ cursor, int* __restrict__ col)
{
    const int e = blockIdx.x * 256 + threadIdx.x;
    if (e < EE) {
        const int p = atomicAdd(&cursor[dst[e]], 1);
        col[p] = src[e];
    }
}

// ------------- fused score + softmax (no-max, fp32-safe) + agg + ELU -------
// one wave per destination node; edges unrolled x8; all node tensors bf16
__global__ __launch_bounds__(256) void gather_kernel(
    const unsigned short* __restrict__ xlb, const unsigned short* __restrict__ xrb,
    const unsigned short* __restrict__ resb,
    const int* __restrict__ rowptr, const int* __restrict__ col,
    const float* __restrict__ att,
    float* __restrict__ outf, unsigned short* __restrict__ outb)
{
    const int node = (blockIdx.x * 256 + threadIdx.x) >> 6;
    const int lane = threadIdx.x & 63;
    if (node >= NN) return;

    const ushort2 xru = ((const ushort2*)(xrb + (size_t)node * DD))[lane];
    const float xr0 = bf2f(xru.x), xr1 = bf2f(xru.y);
    const float2 attv = ((const float2*)att)[lane];

    float d = 0.f, acc0 = 0.f, acc1 = 0.f;
    const int beg = rowptr[node], end = rowptr[node + 1];
    for (int p = beg; p < end; p += 8) {
        float ax[8], ay[8], aa[8];
#pragma unroll
        for (int i = 0; i < 8; ++i) {
            const int q = (p + i < end) ? (p + i) : p;
            const int s = col[q];
            const ushort2 u = ((const ushort2*)(xlb + (size_t)s * DD))[lane];
            ax[i] = bf2f(u.x);
            ay[i] = bf2f(u.y);
        }
#pragma unroll
        for (int i = 0; i < 8; ++i) {
            float z0 = ax[i] + xr0;
            float z1 = ay[i] + xr1;
            z0 = fmaxf(z0, NEG_SLOPE * z0);   // leaky_relu
            z1 = fmaxf(z1, NEG_SLOPE * z1);
            aa[i] = z0 * attv.x + z1 * attv.y;
        }
#pragma unroll
        for (int o = 1; o <= 8; o <<= 1) {
#pragma unroll
            for (int i = 0; i < 8; ++i) aa[i] += __shfl_xor(aa[i], o);
        }
#pragma unroll
        for (int i = 0; i < 8; ++i) {
            float w = __expf(aa[i]);
            w = (p + i < end) ? w : 0.f;
            d    += w;
            acc0 += w * ax[i];
            acc1 += w * ay[i];
        }
    }
    const float inv = 1.f / (d + 1e-16f);
    const ushort2 ru = ((const ushort2*)(resb + (size_t)node * DD))[lane];
    float o0 = acc0 * inv + bf2f(ru.x);
    float o1 = acc1 * inv + bf2f(ru.y);
    o0 = (o0 > 0.f) ? o0 : expm1f(o0);
    o1 = (o1 > 0.f) ? o1 : expm1f(o1);
    if (outf) ((float2*)(outf + (size_t)node * DD))[lane] = make_float2(o0, o1);
    if (outb) {
        ushort2 ob; ob.x = f2bf(o0); ob.y = f2bf(o1);
        ((ushort2*)(outb + (size_t)node * DD))[lane] = ob;
    }
}

extern "C" void kernel_launch(void* const* d_in, const int* in_sizes, int n_in,
                              void* d_out, int out_size, void* d_ws, size_t ws_size,
                              hipStream_t stream)
{
    const float* x0   = (const float*)d_in[0];
    const int*   ei   = (const int*)  d_in[1];
    const float* Wl   = (const float*)d_in[2];
    const float* bl   = (const float*)d_in[3];
    const float* Wr   = (const float*)d_in[4];
    const float* br   = (const float*)d_in[5];
    const float* att  = (const float*)d_in[6];
    const float* Wres = (const float*)d_in[7];
    const float* bias = (const float*)d_in[8];
    const int* src = ei;
    const int* dst = ei + EE;

    float* p = (float*)d_ws;
    unsigned short* xlb  = (unsigned short*)p; p += (size_t)NN * DD / 2;
    unsigned short* xrb  = (unsigned short*)p; p += (size_t)NN * DD / 2;
    unsigned short* resb = (unsigned short*)p; p += (size_t)NN * DD / 2;
    unsigned short* xb0  = (unsigned short*)p; p += (size_t)NN * DD / 2;
    unsigned short* xb1  = (unsigned short*)p; p += (size_t)NN * DD / 2;
    unsigned short* Wb   = (unsigned short*)p; p += 6 * 8192 / 2;
    int* rowptr = (int*)p; p += NN + 1;
    int* deg    = (int*)p; p += NN;
    int* cursor = (int*)p; p += NN;
    int* blksum = (int*)p; p += NBLK;
    int* col    = (int*)p; p += EE;

    // CSR build (dst fixed across layers)
    zero_deg_kernel<<<NBLK, 256, 0, stream>>>(deg);
    hist_kernel<<<(EE + 255) / 256, 256, 0, stream>>>(dst, deg);
    scan1_kernel<<<NBLK, 256, 0, stream>>>(deg, rowptr, blksum);
    scan2_kernel<<<1, 256, 0, stream>>>(blksum);
    scan3_kernel<<<NBLK, 256, 0, stream>>>(rowptr, blksum, cursor);
    fill_kernel<<<(EE + 255) / 256, 256, 0, stream>>>(src, dst, cursor, col);

    cvt_kernel<<<(NN * DD / 4 + 255) / 256, 256, 0, stream>>>(x0, xb0);

    for (int l = 0; l < LL; ++l) {
        const unsigned short* xin = (l == 0) ? xb0 : xb1;
        prepw_kernel<<<192, 256, 0, stream>>>(
            Wl + (size_t)l * DD * DD, Wr + (size_t)l * DD * DD,
            Wres + (size_t)l * DD * DD, Wb);
        gemm_mfma_kernel<<<dim3(NN / 64, 6), 256, 0, stream>>>(
            xin, Wb, bl + l * DD, br + l * DD, bias + l * DD, xlb, xrb, resb);
        gather_kernel<<<(NN * 64 + 255) / 256, 256, 0, stream>>>(
            xlb, xrb, resb, rowptr, col, att + (size_t)l * HH * CC,
            (l == LL - 1) ? (float*)d_out : nullptr,
            (l == 0) ? xb1 : nullptr);
    }
}

// Round 6
// 190.727 us; speedup vs baseline: 5.5489x; 1.0535x over previous
//
#include <hip/hip_runtime.h>
#include <cstdint>

#define NN 40000
#define EE 640000
#define DD 128
#define HH 4
#define CC 32
#define LL 2
#define NEG_SLOPE 0.2f
#define NBLK 157   // ceil(NN/256)

typedef __attribute__((ext_vector_type(8))) short bf16x8;
typedef __attribute__((ext_vector_type(4))) float f32x4;

__device__ __forceinline__ unsigned short f2bf(float f) {
    unsigned u = __float_as_uint(f);
    unsigned r = (u + 0x7FFFu + ((u >> 16) & 1)) >> 16;
    return (unsigned short)r;
}
__device__ __forceinline__ float bf2f(unsigned short u) {
    return __uint_as_float(((unsigned)u) << 16);
}

__device__ __forceinline__ void gload16(const void* g, void* l) {
    __builtin_amdgcn_global_load_lds(
        (const __attribute__((address_space(1))) unsigned*)g,
        (__attribute__((address_space(3))) unsigned*)l, 16, 0, 0);
}

// x fp32 -> bf16 bits
__global__ __launch_bounds__(256) void cvt_kernel(
    const float* __restrict__ in, unsigned short* __restrict__ out)
{
    const int i = blockIdx.x * 256 + threadIdx.x;   // i < NN*DD/4
    if (i >= NN * DD / 4) return;
    const float4 v = ((const float4*)in)[i];
    ushort4 o;
    o.x = f2bf(v.x); o.y = f2bf(v.y); o.z = f2bf(v.z); o.w = f2bf(v.w);
    ((ushort4*)out)[i] = o;
}

// Pack W for BOTH layers (fp32 [L][128][128] k-major, 3 matrices) into bf16
// fragment order: Wb[l*49152 + nb*8192 + q*512 + n*8 + j]
//   = W_sel[l][k = (q>>2)*32 + (q&3)*8 + j][(nb&1)*64 + n]
__global__ __launch_bounds__(256) void prepw_kernel(
    const float* __restrict__ Wl, const float* __restrict__ Wr,
    const float* __restrict__ Wres, unsigned short* __restrict__ Wb)
{
    const int i = blockIdx.x * 256 + threadIdx.x;   // i < 2*6*8192
    if (i >= LL * 6 * 8192) return;
    const int l = i / 49152;
    const int rem0 = i - l * 49152;
    const int nb = rem0 >> 13;
    const int rem = rem0 & 8191;
    const int q = rem >> 9;
    const int n = (rem >> 3) & 63;
    const int j = rem & 7;
    const int k = (q >> 2) * 32 + (q & 3) * 8 + j;
    const int colg = (nb & 1) * 64 + n;
    const float* W = (nb < 2) ? Wl : (nb < 4) ? Wr : Wres;
    Wb[i] = f2bf(W[(size_t)l * DD * DD + k * DD + colg]);
}

// MFMA GEMM: [40000][384] = x_bf16 @ [Wl|Wr|Wres] + bias -> xl/xr/res all bf16.
// Block = 64 rows x 64 cols; grid (625, 6); 4 waves, each 32x32 (2x2 MFMA tiles).
__global__ __launch_bounds__(256) void gemm_mfma_kernel(
    const unsigned short* __restrict__ xb, const unsigned short* __restrict__ Wb,
    const float* __restrict__ bl, const float* __restrict__ br,
    const float* __restrict__ bias,
    unsigned short* __restrict__ xlb, unsigned short* __restrict__ xrb,
    unsigned short* __restrict__ resb)
{
    __shared__ __align__(16) unsigned short lds[16384];  // A:0..8191, B:8192..16383
    const int lane = threadIdx.x & 63;
    const int wv = threadIdx.x >> 6;
    const int row0 = blockIdx.x << 6;
    const int nb = blockIdx.y;

#pragma unroll
    for (int j = 0; j < 4; ++j) {
        const int q = j * 4 + wv;
        gload16(xb + (size_t)(row0 + lane) * DD + q * 8, &lds[q * 512]);
        gload16(Wb + nb * 8192 + q * 512 + lane * 8, &lds[8192 + q * 512]);
    }
    __syncthreads();

    const int wm = wv >> 1, wn = wv & 1;
    const int h = lane >> 4, r = lane & 15;
    f32x4 acc[2][2] = {{{0.f,0.f,0.f,0.f},{0.f,0.f,0.f,0.f}},
                       {{0.f,0.f,0.f,0.f},{0.f,0.f,0.f,0.f}}};
#pragma unroll
    for (int s = 0; s < 4; ++s) {
        const int base = (s * 4 + h) * 64;
        const bf16x8 a0 = *(const bf16x8*)&lds[(base + wm * 32 + r) * 8];
        const bf16x8 a1 = *(const bf16x8*)&lds[(base + wm * 32 + 16 + r) * 8];
        const bf16x8 b0 = *(const bf16x8*)&lds[8192 + (base + wn * 32 + r) * 8];
        const bf16x8 b1 = *(const bf16x8*)&lds[8192 + (base + wn * 32 + 16 + r) * 8];
        acc[0][0] = __builtin_amdgcn_mfma_f32_16x16x32_bf16(a0, b0, acc[0][0], 0, 0, 0);
        acc[0][1] = __builtin_amdgcn_mfma_f32_16x16x32_bf16(a0, b1, acc[0][1], 0, 0, 0);
        acc[1][0] = __builtin_amdgcn_mfma_f32_16x16x32_bf16(a1, b0, acc[1][0], 0, 0, 0);
        acc[1][1] = __builtin_amdgcn_mfma_f32_16x16x32_bf16(a1, b1, acc[1][1], 0, 0, 0);
    }

    unsigned short* const outp = (nb < 2) ? xlb : (nb < 4) ? xrb : resb;
    const float* const bp = (nb < 2) ? bl : (nb < 4) ? br : bias;
    const int c0 = (nb & 1) * 64 + wn * 32;
#pragma unroll
    for (int ni = 0; ni < 2; ++ni) {
        const int col = c0 + ni * 16 + r;
        const float bv = bp[col];
#pragma unroll
        for (int mi = 0; mi < 2; ++mi) {
            const int rw = row0 + wm * 32 + mi * 16 + h * 4;
#pragma unroll
            for (int v = 0; v < 4; ++v)
                outp[(size_t)(rw + v) * DD + col] = f2bf(acc[mi][ni][v] + bv);
        }
    }
}

// ---------------- CSR build (once per call; dst is layer-invariant) --------

__global__ __launch_bounds__(256) void zero_deg_kernel(int* __restrict__ deg)
{
    const int i = blockIdx.x * 256 + threadIdx.x;
    if (i < NN) deg[i] = 0;
}

__global__ __launch_bounds__(256) void hist_kernel(
    const int* __restrict__ dst, int* __restrict__ deg)
{
    const int e = blockIdx.x * 256 + threadIdx.x;
    if (e < EE) atomicAdd(&deg[dst[e]], 1);
}

__global__ __launch_bounds__(256) void scan1_kernel(
    const int* __restrict__ deg, int* __restrict__ rowptr, int* __restrict__ blksum)
{
    __shared__ int s[256];
    const int i = blockIdx.x * 256 + threadIdx.x;
    const int v = (i < NN) ? deg[i] : 0;
    s[threadIdx.x] = v;
    __syncthreads();
    for (int off = 1; off < 256; off <<= 1) {
        const int t = (threadIdx.x >= off) ? s[threadIdx.x - off] : 0;
        __syncthreads();
        s[threadIdx.x] += t;
        __syncthreads();
    }
    if (i < NN) rowptr[i] = s[threadIdx.x] - v;
    if (threadIdx.x == 255) blksum[blockIdx.x] = s[255];
}

__global__ __launch_bounds__(256) void scan2_kernel(int* __restrict__ blksum)
{
    __shared__ int s[256];
    const int v = (threadIdx.x < NBLK) ? blksum[threadIdx.x] : 0;
    s[threadIdx.x] = v;
    __syncthreads();
    for (int off = 1; off < 256; off <<= 1) {
        const int t = (threadIdx.x >= off) ? s[threadIdx.x - off] : 0;
        __syncthreads();
        s[threadIdx.x] += t;
        __syncthreads();
    }
    if (threadIdx.x < NBLK) blksum[threadIdx.x] = s[threadIdx.x] - v;
}

__global__ __launch_bounds__(256) void scan3_kernel(
    int* __restrict__ rowptr, const int* __restrict__ blksum, int* __restrict__ cursor)
{
    const int i = blockIdx.x * 256 + threadIdx.x;
    if (i < NN) {
        const int v = rowptr[i] + blksum[blockIdx.x];
        rowptr[i] = v;
        cursor[i] = v;
    }
    if (i == 0) rowptr[NN] = EE;
}

__global__ __launch_bounds__(256) void fill_kernel(
    const int* __restrict__ src, const int* __restrict__ dst,
    int* __restrict__ cursor, int* __restrict__ col)
{
    const int e = blockIdx.x * 256 + threadIdx.x;
    if (e < EE) {
        const int p = atomicAdd(&cursor[dst[e]], 1);
        col[p] = src[e];
    }
}

// ------------- fused score + softmax (no-max, fp32-safe) + agg + ELU -------
// one wave per dst node; lane owns 4 channels (head = (lane&31)>>3);
// wave-halves process disjoint edge subsets; 8 edges (2x4 slots) per chunk
__global__ __launch_bounds__(256) void gather_kernel(
    const unsigned short* __restrict__ xlb, const unsigned short* __restrict__ xrb,
    const unsigned short* __restrict__ resb,
    const int* __restrict__ rowptr, const int* __restrict__ col,
    const float* __restrict__ att,
    float* __restrict__ outf, unsigned short* __restrict__ outb)
{
    const int node = (blockIdx.x * 256 + threadIdx.x) >> 6;
    const int lane = threadIdx.x & 63;
    if (node >= NN) return;
    const int halfid = lane >> 5;
    const int hl = lane & 31;          // owns channels [hl*4, hl*4+4)

    const ushort4 xru = ((const ushort4*)(xrb + (size_t)node * DD))[hl];
    const float xr0 = bf2f(xru.x), xr1 = bf2f(xru.y);
    const float xr2 = bf2f(xru.z), xr3 = bf2f(xru.w);
    const float4 attv = ((const float4*)att)[hl];

    float d = 0.f, a0 = 0.f, a1 = 0.f, a2 = 0.f, a3 = 0.f;
    const int beg = rowptr[node], end = rowptr[node + 1];
    for (int p = beg; p < end; p += 8) {
        float xv[4][4], al[4];
        int vl[4];
#pragma unroll
        for (int i = 0; i < 4; ++i) {
            const int q = p + 2 * i + halfid;
            vl[i] = (q < end);
            const int s = col[vl[i] ? q : beg];
            const ushort4 u = ((const ushort4*)(xlb + (size_t)s * DD))[hl];
            xv[i][0] = bf2f(u.x); xv[i][1] = bf2f(u.y);
            xv[i][2] = bf2f(u.z); xv[i][3] = bf2f(u.w);
        }
#pragma unroll
        for (int i = 0; i < 4; ++i) {
            float z0 = xv[i][0] + xr0; z0 = fmaxf(z0, NEG_SLOPE * z0);
            float z1 = xv[i][1] + xr1; z1 = fmaxf(z1, NEG_SLOPE * z1);
            float z2 = xv[i][2] + xr2; z2 = fmaxf(z2, NEG_SLOPE * z2);
            float z3 = xv[i][3] + xr3; z3 = fmaxf(z3, NEG_SLOPE * z3);
            al[i] = z0 * attv.x + z1 * attv.y + z2 * attv.z + z3 * attv.w;
        }
#pragma unroll
        for (int o = 1; o <= 4; o <<= 1) {
#pragma unroll
            for (int i = 0; i < 4; ++i) al[i] += __shfl_xor(al[i], o);
        }
#pragma unroll
        for (int i = 0; i < 4; ++i) {
            const float w = vl[i] ? __expf(al[i]) : 0.f;
            d  += w;
            a0 += w * xv[i][0]; a1 += w * xv[i][1];
            a2 += w * xv[i][2]; a3 += w * xv[i][3];
        }
    }
    // combine the two halves (disjoint edge subsets, same channels)
    d  += __shfl_xor(d, 32);
    a0 += __shfl_xor(a0, 32); a1 += __shfl_xor(a1, 32);
    a2 += __shfl_xor(a2, 32); a3 += __shfl_xor(a3, 32);

    if (halfid == 0) {
        const float inv = 1.f / (d + 1e-16f);
        const ushort4 ru = ((const ushort4*)(resb + (size_t)node * DD))[hl];
        float o0 = a0 * inv + bf2f(ru.x);
        float o1 = a1 * inv + bf2f(ru.y);
        float o2 = a2 * inv + bf2f(ru.z);
        float o3 = a3 * inv + bf2f(ru.w);
        o0 = (o0 > 0.f) ? o0 : expm1f(o0);
        o1 = (o1 > 0.f) ? o1 : expm1f(o1);
        o2 = (o2 > 0.f) ? o2 : expm1f(o2);
        o3 = (o3 > 0.f) ? o3 : expm1f(o3);
        if (outf) {
            float4 ov; ov.x = o0; ov.y = o1; ov.z = o2; ov.w = o3;
            ((float4*)(outf + (size_t)node * DD))[hl] = ov;
        }
        if (outb) {
            ushort4 ob;
            ob.x = f2bf(o0); ob.y = f2bf(o1); ob.z = f2bf(o2); ob.w = f2bf(o3);
            ((ushort4*)(outb + (size_t)node * DD))[hl] = ob;
        }
    }
}

extern "C" void kernel_launch(void* const* d_in, const int* in_sizes, int n_in,
                              void* d_out, int out_size, void* d_ws, size_t ws_size,
                              hipStream_t stream)
{
    const float* x0   = (const float*)d_in[0];
    const int*   ei   = (const int*)  d_in[1];
    const float* Wl   = (const float*)d_in[2];
    const float* bl   = (const float*)d_in[3];
    const float* Wr   = (const float*)d_in[4];
    const float* br   = (const float*)d_in[5];
    const float* att  = (const float*)d_in[6];
    const float* Wres = (const float*)d_in[7];
    const float* bias = (const float*)d_in[8];
    const int* src = ei;
    const int* dst = ei + EE;

    float* p = (float*)d_ws;
    unsigned short* xlb  = (unsigned short*)p; p += (size_t)NN * DD / 2;
    unsigned short* xrb  = (unsigned short*)p; p += (size_t)NN * DD / 2;
    unsigned short* resb = (unsigned short*)p; p += (size_t)NN * DD / 2;
    unsigned short* xb0  = (unsigned short*)p; p += (size_t)NN * DD / 2;
    unsigned short* xb1  = (unsigned short*)p; p += (size_t)NN * DD / 2;
    unsigned short* Wb   = (unsigned short*)p; p += LL * 6 * 8192 / 2;
    int* rowptr = (int*)p; p += NN + 1;
    int* deg    = (int*)p; p += NN;
    int* cursor = (int*)p; p += NN;
    int* blksum = (int*)p; p += NBLK;
    int* col    = (int*)p; p += EE;

    // CSR build (dst fixed across layers)
    zero_deg_kernel<<<NBLK, 256, 0, stream>>>(deg);
    hist_kernel<<<(EE + 255) / 256, 256, 0, stream>>>(dst, deg);
    scan1_kernel<<<NBLK, 256, 0, stream>>>(deg, rowptr, blksum);
    scan2_kernel<<<1, 256, 0, stream>>>(blksum);
    scan3_kernel<<<NBLK, 256, 0, stream>>>(rowptr, blksum, cursor);
    fill_kernel<<<(EE + 255) / 256, 256, 0, stream>>>(src, dst, cursor, col);

    cvt_kernel<<<(NN * DD / 4 + 255) / 256, 256, 0, stream>>>(x0, xb0);
    prepw_kernel<<<(LL * 6 * 8192 + 255) / 256, 256, 0, stream>>>(Wl, Wr, Wres, Wb);

    for (int l = 0; l < LL; ++l) {
        const unsigned short* xin = (l == 0) ? xb0 : xb1;
        gemm_mfma_kernel<<<dim3(NN / 64, 6), 256, 0, stream>>>(
            xin, Wb + (size_t)l * 6 * 8192, bl + l * DD, br + l * DD, bias + l * DD,
            xlb, xrb, resb);
        gather_kernel<<<(NN * 64 + 255) / 256, 256, 0, stream>>>(
            xlb, xrb, resb, rowptr, col, att + (size_t)l * HH * CC,
            (l == LL - 1) ? (float*)d_out : nullptr,
            (l == 0) ? xb1 : nullptr);
    }
}